// Round 1
// baseline (317.837 us; speedup 1.0000x reference)
//
#include <hip/hip_runtime.h>
#include <hip/hip_bf16.h>
#include <stdint.h>

#define N_NODES 100000
#define DEG 16
#define D_IN 128
#define D_OUT 256
#define K_TOP 32
#define K_CAT 256   // concatenated K = D_IN(self) + D_IN(neigh)

typedef __attribute__((ext_vector_type(8))) short short8;
typedef __attribute__((ext_vector_type(4))) float floatx4;

__device__ __forceinline__ unsigned pack_bf16_rne(float f) {
    union { float f; unsigned u; } c; c.f = f;
    unsigned u = c.u;
    return (u + 0x7fffu + ((u >> 16) & 1u)) >> 16;   // round-to-nearest-even
}
__device__ __forceinline__ float bf16lo_to_f(unsigned lo16) {
    union { unsigned u; float f; } c; c.u = lo16 << 16; return c.f;
}

// ---------------- kernel 1: pack [w_self | w_neigh] -> bf16 B[256][256] ----------------
__global__ __launch_bounds__(256) void k_packw(const float* __restrict__ w_self,
                                               const float* __restrict__ w_neigh,
                                               unsigned short* __restrict__ bmat) {
    int o = blockIdx.x;      // 0..255 output channel
    int k = threadIdx.x;     // 0..255 concat-K
    float v = (k < D_IN) ? w_self[o * D_IN + k] : w_neigh[o * D_IN + (k - D_IN)];
    bmat[o * K_CAT + k] = (unsigned short)pack_bf16_rne(v);
}

// ---------------- kernel 2: densify k-sparse features -> bf16 x[N][128] ----------------
// One thread per row; private 128-float LDS row (fp32 accumulate handles duplicate
// indices, no atomics). Coalesced bf16 writeback.
__global__ __launch_bounds__(128) void k_densify(const float* __restrict__ topk_v,
                                                 const int* __restrict__ topk_i,
                                                 unsigned short* __restrict__ xbf) {
    __shared__ float sx[128 * 128];   // 64 KiB
    int t = threadIdx.x;
    int row = blockIdx.x * 128 + t;
    for (int i = t; i < 128 * 128; i += 128) sx[i] = 0.f;
    __syncthreads();
    if (row < N_NODES) {
        const float* v = topk_v + (size_t)row * K_TOP;
        const int*  ix = topk_i + (size_t)row * K_TOP;
        float* myrow = sx + t * 128;
        #pragma unroll
        for (int j = 0; j < K_TOP; ++j) myrow[ix[j]] += v[j];
    }
    __syncthreads();
    size_t base = (size_t)blockIdx.x * (128 * 128);
    for (int i = t; i < 128 * 128; i += 128) {
        int r = blockIdx.x * 128 + (i >> 7);
        if (r < N_NODES) xbf[base + i] = (unsigned short)pack_bf16_rne(sx[i]);
    }
}

// ---------------- kernel 3: SpMM (one wave per row) + feat->bf16 convert ----------------
// Writes concatenated A = [feat_bf16 | agg_bf16], row-major [N][256].
__global__ __launch_bounds__(256) void k_spmm(const float* __restrict__ feat,
                                              const float* __restrict__ csr_w,
                                              const int* __restrict__ col_idx,
                                              const unsigned short* __restrict__ xbf,
                                              unsigned short* __restrict__ abf) {
    int wave = threadIdx.x >> 6;
    int lane = threadIdx.x & 63;
    int row  = blockIdx.x * 4 + wave;
    if (row >= N_NODES) return;

    // convert this row's feat to bf16 (lane handles cols 2*lane, 2*lane+1)
    const float2 f2 = *(const float2*)(feat + (size_t)row * D_IN + 2 * lane);
    unsigned fp = pack_bf16_rne(f2.x) | (pack_bf16_rne(f2.y) << 16);
    ((unsigned*)(abf + (size_t)row * K_CAT))[lane] = fp;

    // 16 edges: lanes 0..15 load (col, w), broadcast via shuffle
    int c = 0; float w = 0.f;
    if (lane < DEG) {
        c = col_idx[row * DEG + lane];
        w = csr_w[row * DEG + lane];
    }
    float a0 = 0.f, a1 = 0.f;
    #pragma unroll
    for (int e = 0; e < DEG; ++e) {
        int col  = __shfl(c, e);
        float we = __shfl(w, e);
        unsigned v = ((const unsigned*)(xbf + (size_t)col * D_IN))[lane]; // 2 bf16
        a0 += we * bf16lo_to_f(v & 0xffffu);
        a1 += we * bf16lo_to_f(v >> 16);
    }
    unsigned ap = pack_bf16_rne(a0) | (pack_bf16_rne(a1) << 16);
    ((unsigned*)(abf + (size_t)row * K_CAT + D_IN))[lane] = ap;
}

// ---------------- kernel 4: GEMM  out[N][256] = A[N][256] @ B[256][256]^T + bias -------
#define BM 128
#define BN 128
#define BK 32
#define LDP 40   // padded LDS row stride in shorts (80 B = 20 banks -> 2-way, free)

__global__ __launch_bounds__(256) void k_gemm(const unsigned short* __restrict__ abf,
                                              const unsigned short* __restrict__ bmat,
                                              const float* __restrict__ bias,
                                              float* __restrict__ out) {
    __shared__ unsigned short As[BM * LDP];
    __shared__ unsigned short Bs[BN * LDP];
    int t = threadIdx.x;
    int lane = t & 63, wave = t >> 6;
    int wr = wave >> 1, wc = wave & 1;           // 2x2 wave grid, 64x64 per wave
    int row0 = blockIdx.x * BM;
    int col0 = blockIdx.y * BN;

    floatx4 acc[4][4];
    #pragma unroll
    for (int i = 0; i < 4; ++i)
        #pragma unroll
        for (int j = 0; j < 4; ++j)
            acc[i][j] = (floatx4){0.f, 0.f, 0.f, 0.f};

    int quad = lane >> 4;
    int l16  = lane & 15;

    for (int kt = 0; kt < K_CAT; kt += BK) {
        __syncthreads();
        // stage A,B tiles: 128 rows x 32 shorts (64 B/row) each; 2 x 16B chunks/thread
        #pragma unroll
        for (int p = 0; p < 2; ++p) {
            int chunk = t + p * 256;             // 0..511
            int r  = chunk >> 2;                 // 0..127
            int ko = (chunk & 3) * 8;            // 0,8,16,24
            uint4 av = make_uint4(0u, 0u, 0u, 0u);
            int gr = row0 + r;
            if (gr < N_NODES)
                av = *(const uint4*)(abf + (size_t)gr * K_CAT + kt + ko);
            *(uint4*)&As[r * LDP + ko] = av;
            uint4 bv = *(const uint4*)(bmat + (size_t)(col0 + r) * K_CAT + kt + ko);
            *(uint4*)&Bs[r * LDP + ko] = bv;
        }
        __syncthreads();

        short8 afr[4], bfr[4];
        #pragma unroll
        for (int i = 0; i < 4; ++i) {
            int m = wr * 64 + i * 16 + l16;      // A[m][k]: m=lane&15, k=quad*8+j
            afr[i] = *(const short8*)&As[m * LDP + quad * 8];
        }
        #pragma unroll
        for (int j = 0; j < 4; ++j) {
            int n = wc * 64 + j * 16 + l16;      // B[k][n]: n=lane&15, k=quad*8+j
            bfr[j] = *(const short8*)&Bs[n * LDP + quad * 8];
        }
        #pragma unroll
        for (int i = 0; i < 4; ++i)
            #pragma unroll
            for (int j = 0; j < 4; ++j)
                acc[i][j] = __builtin_amdgcn_mfma_f32_16x16x32_bf16(afr[i], bfr[j], acc[i][j], 0, 0, 0);
    }

    // epilogue: D frag mapping col=lane&15, row=quad*4+reg
    #pragma unroll
    for (int j = 0; j < 4; ++j) {
        int cg = col0 + wc * 64 + j * 16 + l16;
        float bv = bias[cg];
        #pragma unroll
        for (int i = 0; i < 4; ++i) {
            int mbase = row0 + wr * 64 + i * 16 + quad * 4;
            #pragma unroll
            for (int r = 0; r < 4; ++r) {
                int gr = mbase + r;
                if (gr < N_NODES) out[(size_t)gr * D_OUT + cg] = acc[i][j][r] + bv;
            }
        }
    }
}

extern "C" void kernel_launch(void* const* d_in, const int* in_sizes, int n_in,
                              void* d_out, int out_size, void* d_ws, size_t ws_size,
                              hipStream_t stream) {
    const float* feat    = (const float*)d_in[0];
    const float* topk_v  = (const float*)d_in[1];
    const float* csr_w   = (const float*)d_in[2];
    const float* w_neigh = (const float*)d_in[3];
    const float* w_self  = (const float*)d_in[4];
    const float* b_self  = (const float*)d_in[5];
    const int*   topk_i  = (const int*)d_in[6];
    // d_in[7] = indptr (fixed degree 16, unused), d_in[8] = indices
    const int*   indices = (const int*)d_in[8];
    float* out = (float*)d_out;

    // workspace layout (bf16): x[N*128] | A[N*256] | B[256*256]  (~77 MB)
    unsigned short* xbf  = (unsigned short*)d_ws;
    unsigned short* abf  = xbf + (size_t)N_NODES * D_IN;
    unsigned short* bmat = abf + (size_t)N_NODES * K_CAT;

    k_packw<<<dim3(256), dim3(256), 0, stream>>>(w_self, w_neigh, bmat);
    k_densify<<<dim3((N_NODES + 127) / 128), dim3(128), 0, stream>>>(topk_v, topk_i, xbf);
    k_spmm<<<dim3(N_NODES / 4), dim3(256), 0, stream>>>(feat, csr_w, indices, xbf, abf);
    dim3 g((N_NODES + BM - 1) / BM, D_OUT / BN);
    k_gemm<<<g, dim3(256), 0, stream>>>(abf, bmat, b_self, out);
}